// Round 8
// baseline (222.176 us; speedup 1.0000x reference)
//
#include <hip/hip_runtime.h>
#include <hip/hip_fp16.h>

// ---------------------------------------------------------------------------
// GCN layer: out[b][f][t][n] = relu( rsqrt(deg_in[n]) *
//     sum_{e: dst[e]=n} ( rsqrt(deg_out[src[e]]) * x[src[e]] @ W )[b][t][f] + bias[f] )
// Strategy: (1) degrees+CSR, (2) GEMV-style transform -> y[n][512] fp16
//           node-major, (3) CSR gather-sum + epilogue + transpose-back.
// R7: transform processes 2 nodes/lane (float2 x-loads): halves load/addr/W
//     events per FMA, unroll4 covers ~512 compute cycles per 4 in-flight
//     loads. acc0[32]+acc1[32] static-indexed (avoid R3/R6 spill trap).
// ---------------------------------------------------------------------------

extern "C" __global__ void k_zero(int* __restrict__ p, int n) {
  int i = blockIdx.x * blockDim.x + threadIdx.x;
  if (i < n) p[i] = 0;
}

extern "C" __global__ void k_deg(const int* __restrict__ src, const int* __restrict__ dst,
                                 int* __restrict__ deg_out, int* __restrict__ deg_in, int E) {
  int e = blockIdx.x * blockDim.x + threadIdx.x;
  if (e < E) {
    atomicAdd(&deg_out[src[e]], 1);
    atomicAdd(&deg_in[dst[e]], 1);
  }
}

extern "C" __global__ void k_rsqrt(const int* __restrict__ dgo, const int* __restrict__ dgi,
                                   float* __restrict__ rs_out, float* __restrict__ rs_in, int N) {
  int i = blockIdx.x * blockDim.x + threadIdx.x;
  if (i < N) {
    int a = dgo[i] > 1 ? dgo[i] : 1;
    int b = dgi[i] > 1 ? dgi[i] : 1;
    rs_out[i] = rsqrtf((float)a);
    rs_in[i]  = rsqrtf((float)b);
  }
}

// --- 3-phase exclusive scan of deg_in -> offs (N <= 65536: block sums <= 256)
extern "C" __global__ __launch_bounds__(256) void k_scan1(const int* __restrict__ deg,
                                                          int* __restrict__ bsum, int N) {
  __shared__ int red[256];
  int tid = threadIdx.x;
  int i = blockIdx.x * 256 + tid;
  red[tid] = (i < N) ? deg[i] : 0;
  __syncthreads();
  #pragma unroll
  for (int off = 128; off > 0; off >>= 1) {
    if (tid < off) red[tid] += red[tid + off];
    __syncthreads();
  }
  if (tid == 0) bsum[blockIdx.x] = red[0];
}

extern "C" __global__ __launch_bounds__(256) void k_scan2(const int* __restrict__ bsum,
                                                          int* __restrict__ boffs,
                                                          int* __restrict__ offs, int M, int N) {
  __shared__ int sc[256];
  int tid = threadIdx.x;
  int v = (tid < M) ? bsum[tid] : 0;
  sc[tid] = v;
  __syncthreads();
  #pragma unroll
  for (int off = 1; off < 256; off <<= 1) {
    int t = sc[tid];
    if (tid >= off) t += sc[tid - off];
    __syncthreads();
    sc[tid] = t;
    __syncthreads();
  }
  boffs[tid] = sc[tid] - v;           // exclusive block offset
  if (tid == 255) offs[N] = sc[255];  // total edge count
}

extern "C" __global__ __launch_bounds__(256) void k_scan3(const int* __restrict__ deg,
                                                          const int* __restrict__ boffs,
                                                          int* __restrict__ offs, int N) {
  __shared__ int sc[256];
  int tid = threadIdx.x;
  int i = blockIdx.x * 256 + tid;
  int v = (i < N) ? deg[i] : 0;
  sc[tid] = v;
  __syncthreads();
  #pragma unroll
  for (int off = 1; off < 256; off <<= 1) {
    int t = sc[tid];
    if (tid >= off) t += sc[tid - off];
    __syncthreads();
    sc[tid] = t;
    __syncthreads();
  }
  if (i < N) offs[i] = boffs[blockIdx.x] + sc[tid] - v;
}

extern "C" __global__ void k_scatter(const int* __restrict__ src, const int* __restrict__ dst,
                                     const int* __restrict__ offs, int* __restrict__ cursor,
                                     int* __restrict__ csr_src, int E) {
  int e = blockIdx.x * blockDim.x + threadIdx.x;
  if (e < E) {
    int d = dst[e];
    int pos = offs[d] + atomicAdd(&cursor[d], 1);
    csr_src[pos] = src[e];
  }
}

// y[n][(b*4+t)*64 + f] (fp16) = rs_out[n] * sum_h x[((b*64+h)*4+t)*N + n] * W[h*64+f]
// wave = 128 nodes (lane -> nodes 2*lane, 2*lane+1) x one bt x 32 f's.
// blockIdx.y picks the bt quad, blockIdx.z the f half. One float2 x-load per
// h covers 2 nodes: halves load/addr/W-scalar events per FMA. acc fp32.
// NOTE: h-loop unroll stays at 4 — unroll 8 overflows the reg budget (R6).
extern "C" __global__ __launch_bounds__(256) void k_transform(
    const float* __restrict__ in_feat, const float* __restrict__ W,
    const float* __restrict__ rs_out, __half* __restrict__ y, int N) {
  int tid = threadIdx.x;
  int wave = tid >> 6, lane = tid & 63;
  int bt = blockIdx.y * 4 + wave;     // 0..7
  int b = bt >> 2, t = bt & 3;
  int fh = blockIdx.z * 32;           // f half: 0 or 32
  int n = blockIdx.x * 128 + lane * 2;

  const float* xp = in_feat + (size_t)(b * 256 + t) * (size_t)N;  // h=0 row
  size_t hstride = (size_t)4 * (size_t)N;

  float acc0[32], acc1[32];
  #pragma unroll
  for (int f = 0; f < 32; ++f) { acc0[f] = 0.0f; acc1[f] = 0.0f; }

  bool ok0 = (n < N), ok1 = (n + 1 < N);
  #pragma unroll 4
  for (int h = 0; h < 64; ++h) {
    float2 xv;
    if (ok1) {
      xv = *(const float2*)&xp[(size_t)h * hstride + n];
    } else {
      xv.x = ok0 ? xp[(size_t)h * hstride + n] : 0.0f;
      xv.y = 0.0f;
    }
    const float* wrow = W + h * 64 + fh;   // wave-uniform address -> s_load
    #pragma unroll
    for (int f = 0; f < 32; ++f) {
      acc0[f] = fmaf(xv.x, wrow[f], acc0[f]);
      acc1[f] = fmaf(xv.y, wrow[f], acc1[f]);
    }
  }

  if (ok0) {
    float rs = *(const float*)&rs_out[n];
    union { unsigned int u[16]; uint4 v[4]; } pk;
    #pragma unroll
    for (int q = 0; q < 16; ++q) {
      __half2 h2 = __float22half2_rn(make_float2(acc0[2 * q] * rs, acc0[2 * q + 1] * rs));
      pk.u[q] = *(unsigned int*)&h2;
    }
    uint4* yp = (uint4*)(y + (size_t)n * 512 + bt * 64 + fh);
    #pragma unroll
    for (int q = 0; q < 4; ++q) yp[q] = pk.v[q];
  }
  if (ok1) {
    float rs = rs_out[n + 1];
    union { unsigned int u[16]; uint4 v[4]; } pk;
    #pragma unroll
    for (int q = 0; q < 16; ++q) {
      __half2 h2 = __float22half2_rn(make_float2(acc1[2 * q] * rs, acc1[2 * q + 1] * rs));
      pk.u[q] = *(unsigned int*)&h2;
    }
    uint4* yp = (uint4*)(y + (size_t)(n + 1) * 512 + bt * 64 + fh);
    #pragma unroll
    for (int q = 0; q < 4; ++q) yp[q] = pk.v[q];
  }
}

// out[((b*64+f)*4+t)*N + n] = relu( rs_in[n] * sum_{j in CSR(n)} y[csr_src[j]][c] + bias[f] )
// 512 threads = 8 waves; wave handles 2 nodes (16-node tile, 33KB LDS ->
// 4 blocks/CU -> 32 waves/CU). Per node: lane-parallel CSR index block load,
// readlane broadcast, per-edge 2x8B independent loads.
extern "C" __global__ __launch_bounds__(512) void k_aggregate(
    const __half* __restrict__ y, const int* __restrict__ offs,
    const int* __restrict__ csr_src, const float* __restrict__ rs_in,
    const float* __restrict__ bvec, float* __restrict__ out, int N) {
  __shared__ float agg[16 * 513];  // [node][channel], pad -> benign epilogue banks
  int tid = threadIdx.x;
  int lane = tid & 63, wave = tid >> 6;   // 8 waves
  int n0 = blockIdx.x * 16;

#define ACC_EDGE(s)                                                          \
  {                                                                          \
    const uint2* rp = (const uint2*)(y + (size_t)(s) * 512);                 \
    uint2 ua = rp[lane];                                                     \
    uint2 ub = rp[64 + lane];                                                \
    float2 f;                                                                \
    f = __half22float2(*(const __half2*)&ua.x); accA.x += f.x; accA.y += f.y;\
    f = __half22float2(*(const __half2*)&ua.y); accA.z += f.x; accA.w += f.y;\
    f = __half22float2(*(const __half2*)&ub.x); accB.x += f.x; accB.y += f.y;\
    f = __half22float2(*(const __half2*)&ub.y); accB.z += f.x; accB.w += f.y;\
  }

  #pragma unroll
  for (int k = 0; k < 2; ++k) {
    int nl = k * 8 + wave;
    int n = n0 + nl;
    float4 accA = {0.f, 0.f, 0.f, 0.f};
    float4 accB = {0.f, 0.f, 0.f, 0.f};
    if (n < N) {
      int j0 = offs[n], j1 = offs[n + 1];
      for (int base = j0; base < j1; base += 64) {
        int idxv = csr_src[base + lane];  // coalesced block of up to 64 indices
        int m = j1 - base; if (m > 64) m = 64;
        int e = 0;
        for (; e + 3 < m; e += 4) {
          int s0 = __builtin_amdgcn_readlane(idxv, e);
          int s1 = __builtin_amdgcn_readlane(idxv, e + 1);
          int s2 = __builtin_amdgcn_readlane(idxv, e + 2);
          int s3 = __builtin_amdgcn_readlane(idxv, e + 3);
          ACC_EDGE(s0); ACC_EDGE(s1); ACC_EDGE(s2); ACC_EDGE(s3);
        }
        for (; e < m; ++e) {
          int s0 = __builtin_amdgcn_readlane(idxv, e);
          ACC_EDGE(s0);
        }
      }
    }
    *(float4*)&agg[nl * 513 + lane * 4] = accA;
    *(float4*)&agg[nl * 513 + 256 + lane * 4] = accB;
  }
#undef ACC_EDGE
  __syncthreads();

  // epilogue: scale, bias, relu, transpose-back to channel-major
  int nl = tid & 15;
  int r0 = tid >> 4;  // 0..31
  int n = n0 + nl;
  float rs = (n < N) ? rs_in[n] : 0.0f;
  #pragma unroll 4
  for (int it = 0; it < 16; ++it) {
    int c = it * 32 + r0;          // c = (b*4+t)*64 + f
    float v = agg[nl * 513 + c];
    int f = c & 63, bt = c >> 6;
    int b = bt >> 2, t = bt & 3;
    v = v * rs + bvec[f];
    v = fmaxf(v, 0.0f);
    if (n < N) out[(size_t)((b * 64 + f) * 4 + t) * (size_t)N + n] = v;
  }
}

extern "C" void kernel_launch(void* const* d_in, const int* in_sizes, int n_in,
                              void* d_out, int out_size, void* d_ws, size_t ws_size,
                              hipStream_t stream) {
  const float* in_feat = (const float*)d_in[0];
  const int*   src     = (const int*)d_in[1];
  const int*   dst     = (const int*)d_in[2];
  const float* W       = (const float*)d_in[3];
  const float* bvec    = (const float*)d_in[4];
  float* out = (float*)d_out;

  int N = in_sizes[0] / 512;   // B*H*T = 2*64*4 = 512
  int E = in_sizes[1];

  int A  = (N + 64) & ~63;     // room for N+1 offsets, 64-aligned
  int EA = (E + 63) & ~63;
  int M  = (N + 255) / 256;    // scan blocks (<= 256 for N <= 65536)

  // layout: the three arrays needing zero-init come first (one contiguous memset)
  int*   deg_out_i = (int*)d_ws;        // [A]  zeroed
  int*   deg_in_i  = deg_out_i + A;     // [A]  zeroed
  int*   cursor    = deg_in_i + A;      // [A]  zeroed
  int*   offs      = cursor + A;        // [A] (N+1 used, fully written by scans)
  int*   bsum      = offs + A;          // [256]
  int*   boffs     = bsum + 256;        // [256]
  float* rs_out    = (float*)(boffs + 256);
  float* rs_in     = rs_out + A;
  int*   csr_src   = (int*)(rs_in + A); // [EA] (+slack: y follows, overreads safe)
  __half* y        = (__half*)(csr_src + EA); // [N*512] fp16

  int z = 3 * A;
  hipLaunchKernelGGL(k_zero, dim3((z + 255) / 256), dim3(256), 0, stream, deg_out_i, z);
  hipLaunchKernelGGL(k_deg, dim3((E + 255) / 256), dim3(256), 0, stream,
                     src, dst, deg_out_i, deg_in_i, E);
  hipLaunchKernelGGL(k_rsqrt, dim3((N + 255) / 256), dim3(256), 0, stream,
                     deg_out_i, deg_in_i, rs_out, rs_in, N);
  hipLaunchKernelGGL(k_scan1, dim3(M), dim3(256), 0, stream, deg_in_i, bsum, N);
  hipLaunchKernelGGL(k_scan2, dim3(1), dim3(256), 0, stream, bsum, boffs, offs, M, N);
  hipLaunchKernelGGL(k_scan3, dim3(M), dim3(256), 0, stream, deg_in_i, boffs, offs, N);
  hipLaunchKernelGGL(k_scatter, dim3((E + 255) / 256), dim3(256), 0, stream,
                     src, dst, offs, cursor, csr_src, E);
  hipLaunchKernelGGL(k_transform, dim3((N + 127) / 128, 2, 2), dim3(256), 0, stream,
                     in_feat, W, rs_out, y, N);
  hipLaunchKernelGGL(k_aggregate, dim3((N + 15) / 16), dim3(512), 0, stream,
                     y, offs, csr_src, rs_in, bvec, out, N);
}

// Round 9
// 196.965 us; speedup vs baseline: 1.1280x; 1.1280x over previous
//
#include <hip/hip_runtime.h>
#include <hip/hip_fp16.h>

// ---------------------------------------------------------------------------
// GCN layer: out[b][f][t][n] = relu( rsqrt(deg_in[n]) *
//     sum_{e: dst[e]=n} ( rsqrt(deg_out[src[e]]) * x[src[e]] @ W )[b][t][f] + bias[f] )
// Strategy: (1) degrees+CSR, (2) GEMV-style transform -> y[n][512] fp16
//           node-major, (3) CSR gather-sum + epilogue + transpose-back.
// R8 post-mortem: 2-nodes/lane spilled (VGPR 52 < 64 acc) + halved grid ->
//     reverted to 1-node/lane (VGPR 28). R9: cross-iteration software
//     prefetch in the h-loop (load group i+1 before FMAs of group i) to kill
//     the ~300-cycle per-group load stall (VALUBusy 39% -> predicted ~70%).
// ---------------------------------------------------------------------------

extern "C" __global__ void k_zero(int* __restrict__ p, int n) {
  int i = blockIdx.x * blockDim.x + threadIdx.x;
  if (i < n) p[i] = 0;
}

extern "C" __global__ void k_deg(const int* __restrict__ src, const int* __restrict__ dst,
                                 int* __restrict__ deg_out, int* __restrict__ deg_in, int E) {
  int e = blockIdx.x * blockDim.x + threadIdx.x;
  if (e < E) {
    atomicAdd(&deg_out[src[e]], 1);
    atomicAdd(&deg_in[dst[e]], 1);
  }
}

extern "C" __global__ void k_rsqrt(const int* __restrict__ dgo, const int* __restrict__ dgi,
                                   float* __restrict__ rs_out, float* __restrict__ rs_in, int N) {
  int i = blockIdx.x * blockDim.x + threadIdx.x;
  if (i < N) {
    int a = dgo[i] > 1 ? dgo[i] : 1;
    int b = dgi[i] > 1 ? dgi[i] : 1;
    rs_out[i] = rsqrtf((float)a);
    rs_in[i]  = rsqrtf((float)b);
  }
}

// --- 3-phase exclusive scan of deg_in -> offs (N <= 65536: block sums <= 256)
extern "C" __global__ __launch_bounds__(256) void k_scan1(const int* __restrict__ deg,
                                                          int* __restrict__ bsum, int N) {
  __shared__ int red[256];
  int tid = threadIdx.x;
  int i = blockIdx.x * 256 + tid;
  red[tid] = (i < N) ? deg[i] : 0;
  __syncthreads();
  #pragma unroll
  for (int off = 128; off > 0; off >>= 1) {
    if (tid < off) red[tid] += red[tid + off];
    __syncthreads();
  }
  if (tid == 0) bsum[blockIdx.x] = red[0];
}

extern "C" __global__ __launch_bounds__(256) void k_scan2(const int* __restrict__ bsum,
                                                          int* __restrict__ boffs,
                                                          int* __restrict__ offs, int M, int N) {
  __shared__ int sc[256];
  int tid = threadIdx.x;
  int v = (tid < M) ? bsum[tid] : 0;
  sc[tid] = v;
  __syncthreads();
  #pragma unroll
  for (int off = 1; off < 256; off <<= 1) {
    int t = sc[tid];
    if (tid >= off) t += sc[tid - off];
    __syncthreads();
    sc[tid] = t;
    __syncthreads();
  }
  boffs[tid] = sc[tid] - v;           // exclusive block offset
  if (tid == 255) offs[N] = sc[255];  // total edge count
}

extern "C" __global__ __launch_bounds__(256) void k_scan3(const int* __restrict__ deg,
                                                          const int* __restrict__ boffs,
                                                          int* __restrict__ offs, int N) {
  __shared__ int sc[256];
  int tid = threadIdx.x;
  int i = blockIdx.x * 256 + tid;
  int v = (i < N) ? deg[i] : 0;
  sc[tid] = v;
  __syncthreads();
  #pragma unroll
  for (int off = 1; off < 256; off <<= 1) {
    int t = sc[tid];
    if (tid >= off) t += sc[tid - off];
    __syncthreads();
    sc[tid] = t;
    __syncthreads();
  }
  if (i < N) offs[i] = boffs[blockIdx.x] + sc[tid] - v;
}

extern "C" __global__ void k_scatter(const int* __restrict__ src, const int* __restrict__ dst,
                                     const int* __restrict__ offs, int* __restrict__ cursor,
                                     int* __restrict__ csr_src, int E) {
  int e = blockIdx.x * blockDim.x + threadIdx.x;
  if (e < E) {
    int d = dst[e];
    int pos = offs[d] + atomicAdd(&cursor[d], 1);
    csr_src[pos] = src[e];
  }
}

// y[n][(b*4+t)*64 + f] (fp16) = rs_out[n] * sum_h x[((b*64+h)*4+t)*N + n] * W[h*64+f]
// wave = 64 nodes (lane = node) x one bt x 32 f's. blockIdx.y picks the bt
// quad, blockIdx.z picks the f half. acc[32] fp32; W via wave-uniform scalar
// loads. Cross-iteration prefetch: xnxt[4] loaded before the FMAs of the
// current group so each group's loads have a full group of compute to hide
// under. VGPR target ~36-40 (R6/R8: bigger per-thread tiles spill).
extern "C" __global__ __launch_bounds__(256) void k_transform(
    const float* __restrict__ in_feat, const float* __restrict__ W,
    const float* __restrict__ rs_out, __half* __restrict__ y, int N) {
  int tid = threadIdx.x;
  int wave = tid >> 6, lane = tid & 63;
  int bt = blockIdx.y * 4 + wave;     // 0..7
  int b = bt >> 2, t = bt & 3;
  int fh = blockIdx.z * 32;           // f half: 0 or 32
  int n = blockIdx.x * 64 + lane;

  const float* xp = in_feat + (size_t)(b * 256 + t) * (size_t)N;  // h=0 row
  size_t hstride = (size_t)4 * (size_t)N;

  float acc[32];
  #pragma unroll
  for (int f = 0; f < 32; ++f) acc[f] = 0.0f;

  bool ok = (n < N);

  float xcur[4], xnxt[4];
  #pragma unroll
  for (int u = 0; u < 4; ++u)
    xcur[u] = ok ? xp[(size_t)u * hstride + n] : 0.0f;

  #pragma unroll 1
  for (int h0 = 0; h0 < 60; h0 += 4) {
    // prefetch next group before consuming this one
    #pragma unroll
    for (int u = 0; u < 4; ++u)
      xnxt[u] = ok ? xp[(size_t)(h0 + 4 + u) * hstride + n] : 0.0f;
    #pragma unroll
    for (int u = 0; u < 4; ++u) {
      const float* wrow = W + (h0 + u) * 64 + fh;   // uniform -> s_load
      #pragma unroll
      for (int f = 0; f < 32; ++f) acc[f] = fmaf(xcur[u], wrow[f], acc[f]);
    }
    #pragma unroll
    for (int u = 0; u < 4; ++u) xcur[u] = xnxt[u];
  }
  // last group (h = 60..63), no prefetch
  #pragma unroll
  for (int u = 0; u < 4; ++u) {
    const float* wrow = W + (60 + u) * 64 + fh;
    #pragma unroll
    for (int f = 0; f < 32; ++f) acc[f] = fmaf(xcur[u], wrow[f], acc[f]);
  }

  if (ok) {
    float rs = rs_out[n];
    union { unsigned int u[16]; uint4 v[4]; } pk;
    #pragma unroll
    for (int q = 0; q < 16; ++q) {
      __half2 h2 = __float22half2_rn(make_float2(acc[2 * q] * rs, acc[2 * q + 1] * rs));
      pk.u[q] = *(unsigned int*)&h2;
    }
    uint4* yp = (uint4*)(y + (size_t)n * 512 + bt * 64 + fh);
    #pragma unroll
    for (int q = 0; q < 4; ++q) yp[q] = pk.v[q];
  }
}

// out[((b*64+f)*4+t)*N + n] = relu( rs_in[n] * sum_{j in CSR(n)} y[csr_src[j]][c] + bias[f] )
// 512 threads = 8 waves; wave handles 2 nodes (16-node tile, 33KB LDS ->
// 4 blocks/CU -> 32 waves/CU). Per node: lane-parallel CSR index block load,
// readlane broadcast, per-edge 2x8B independent loads.
extern "C" __global__ __launch_bounds__(512) void k_aggregate(
    const __half* __restrict__ y, const int* __restrict__ offs,
    const int* __restrict__ csr_src, const float* __restrict__ rs_in,
    const float* __restrict__ bvec, float* __restrict__ out, int N) {
  __shared__ float agg[16 * 513];  // [node][channel], pad -> benign epilogue banks
  int tid = threadIdx.x;
  int lane = tid & 63, wave = tid >> 6;   // 8 waves
  int n0 = blockIdx.x * 16;

#define ACC_EDGE(s)                                                          \
  {                                                                          \
    const uint2* rp = (const uint2*)(y + (size_t)(s) * 512);                 \
    uint2 ua = rp[lane];                                                     \
    uint2 ub = rp[64 + lane];                                                \
    float2 f;                                                                \
    f = __half22float2(*(const __half2*)&ua.x); accA.x += f.x; accA.y += f.y;\
    f = __half22float2(*(const __half2*)&ua.y); accA.z += f.x; accA.w += f.y;\
    f = __half22float2(*(const __half2*)&ub.x); accB.x += f.x; accB.y += f.y;\
    f = __half22float2(*(const __half2*)&ub.y); accB.z += f.x; accB.w += f.y;\
  }

  #pragma unroll
  for (int k = 0; k < 2; ++k) {
    int nl = k * 8 + wave;
    int n = n0 + nl;
    float4 accA = {0.f, 0.f, 0.f, 0.f};
    float4 accB = {0.f, 0.f, 0.f, 0.f};
    if (n < N) {
      int j0 = offs[n], j1 = offs[n + 1];
      for (int base = j0; base < j1; base += 64) {
        int idxv = csr_src[base + lane];  // coalesced block of up to 64 indices
        int m = j1 - base; if (m > 64) m = 64;
        int e = 0;
        for (; e + 3 < m; e += 4) {
          int s0 = __builtin_amdgcn_readlane(idxv, e);
          int s1 = __builtin_amdgcn_readlane(idxv, e + 1);
          int s2 = __builtin_amdgcn_readlane(idxv, e + 2);
          int s3 = __builtin_amdgcn_readlane(idxv, e + 3);
          ACC_EDGE(s0); ACC_EDGE(s1); ACC_EDGE(s2); ACC_EDGE(s3);
        }
        for (; e < m; ++e) {
          int s0 = __builtin_amdgcn_readlane(idxv, e);
          ACC_EDGE(s0);
        }
      }
    }
    *(float4*)&agg[nl * 513 + lane * 4] = accA;
    *(float4*)&agg[nl * 513 + 256 + lane * 4] = accB;
  }
#undef ACC_EDGE
  __syncthreads();

  // epilogue: scale, bias, relu, transpose-back to channel-major
  int nl = tid & 15;
  int r0 = tid >> 4;  // 0..31
  int n = n0 + nl;
  float rs = (n < N) ? rs_in[n] : 0.0f;
  #pragma unroll 4
  for (int it = 0; it < 16; ++it) {
    int c = it * 32 + r0;          // c = (b*4+t)*64 + f
    float v = agg[nl * 513 + c];
    int f = c & 63, bt = c >> 6;
    int b = bt >> 2, t = bt & 3;
    v = v * rs + bvec[f];
    v = fmaxf(v, 0.0f);
    if (n < N) out[(size_t)((b * 64 + f) * 4 + t) * (size_t)N + n] = v;
  }
}

extern "C" void kernel_launch(void* const* d_in, const int* in_sizes, int n_in,
                              void* d_out, int out_size, void* d_ws, size_t ws_size,
                              hipStream_t stream) {
  const float* in_feat = (const float*)d_in[0];
  const int*   src     = (const int*)d_in[1];
  const int*   dst     = (const int*)d_in[2];
  const float* W       = (const float*)d_in[3];
  const float* bvec    = (const float*)d_in[4];
  float* out = (float*)d_out;

  int N = in_sizes[0] / 512;   // B*H*T = 2*64*4 = 512
  int E = in_sizes[1];

  int A  = (N + 64) & ~63;     // room for N+1 offsets, 64-aligned
  int EA = (E + 63) & ~63;
  int M  = (N + 255) / 256;    // scan blocks (<= 256 for N <= 65536)

  // layout: the three arrays needing zero-init come first (one contiguous memset)
  int*   deg_out_i = (int*)d_ws;        // [A]  zeroed
  int*   deg_in_i  = deg_out_i + A;     // [A]  zeroed
  int*   cursor    = deg_in_i + A;      // [A]  zeroed
  int*   offs      = cursor + A;        // [A] (N+1 used, fully written by scans)
  int*   bsum      = offs + A;          // [256]
  int*   boffs     = bsum + 256;        // [256]
  float* rs_out    = (float*)(boffs + 256);
  float* rs_in     = rs_out + A;
  int*   csr_src   = (int*)(rs_in + A); // [EA] (+slack: y follows, overreads safe)
  __half* y        = (__half*)(csr_src + EA); // [N*512] fp16

  int z = 3 * A;
  hipLaunchKernelGGL(k_zero, dim3((z + 255) / 256), dim3(256), 0, stream, deg_out_i, z);
  hipLaunchKernelGGL(k_deg, dim3((E + 255) / 256), dim3(256), 0, stream,
                     src, dst, deg_out_i, deg_in_i, E);
  hipLaunchKernelGGL(k_rsqrt, dim3((N + 255) / 256), dim3(256), 0, stream,
                     deg_out_i, deg_in_i, rs_out, rs_in, N);
  hipLaunchKernelGGL(k_scan1, dim3(M), dim3(256), 0, stream, deg_in_i, bsum, N);
  hipLaunchKernelGGL(k_scan2, dim3(1), dim3(256), 0, stream, bsum, boffs, offs, M, N);
  hipLaunchKernelGGL(k_scan3, dim3(M), dim3(256), 0, stream, deg_in_i, boffs, offs, N);
  hipLaunchKernelGGL(k_scatter, dim3((E + 255) / 256), dim3(256), 0, stream,
                     src, dst, offs, cursor, csr_src, E);
  hipLaunchKernelGGL(k_transform, dim3((N + 63) / 64, 2, 2), dim3(256), 0, stream,
                     in_feat, W, rs_out, y, N);
  hipLaunchKernelGGL(k_aggregate, dim3((N + 15) / 16), dim3(512), 0, stream,
                     y, offs, csr_src, rs_in, bvec, out, N);
}